// Round 5
// baseline (287.008 us; speedup 1.0000x reference)
//
#include <hip/hip_runtime.h>

#define EPS 1e-5f
// B=64, D=2048, E=64, H1=512, H2=256

typedef __attribute__((ext_vector_type(8))) short short8;
typedef __attribute__((ext_vector_type(4))) float f32x4;

__device__ __forceinline__ float bflo(unsigned u) { return __uint_as_float(u << 16); }
__device__ __forceinline__ float bfhi(unsigned u) { return __uint_as_float(u & 0xffff0000u); }
__device__ __forceinline__ unsigned short f2bf(float f) {
  unsigned u = __float_as_uint(f);
  u = u + 0x7FFFu + ((u >> 16) & 1u);  // RNE
  return (unsigned short)(u >> 16);
}
__device__ __forceinline__ unsigned pack2(float a, float b) {
  return (unsigned)f2bf(a) | ((unsigned)f2bf(b) << 16);
}

// ---------------- prep2: everything except the fused GEMM, all independent ----------------
// blocks 0..511   : Q (with pbias folded in) and R, 4 k-values each (emb staged in LDS)
// blocks 512..575 : W2t[o][h] = bf16(W2[h][o])
// blocks 576..703 : Pf[b][h] = a[h] * (rep[b] @ W1d[:,h])  (f32, one b x 256-h half per block)
// block  704      : t2, c2
__global__ __launch_bounds__(256) void prep2(
    const float* __restrict__ rep, const float* __restrict__ emb,
    const float* __restrict__ W1,
    const float* __restrict__ g1, const float* __restrict__ v1,
    const float* __restrict__ b1, const float* __restrict__ m1,
    const float* __restrict__ beta1,
    const float* __restrict__ W2,
    const float* __restrict__ g2, const float* __restrict__ v2,
    const float* __restrict__ b2, const float* __restrict__ m2,
    const float* __restrict__ beta2,
    unsigned* __restrict__ Q, unsigned* __restrict__ R,
    unsigned short* __restrict__ W2t,
    float* __restrict__ t2, float* __restrict__ c2, float* __restrict__ Pf) {
  __shared__ float smem[2048];  // 8 KB: emb rows (QR path) or rep row (Pf path)
  const int x = blockIdx.x, t = threadIdx.x;
  if (x < 512) {
    const int k0 = x * 4;
    smem[t] = emb[x * 256 + t];  // 4 emb rows, coalesced
    __syncthreads();
    const int h = t * 2;
    const float a0 = g1[h] * rsqrtf(v1[h] + EPS);
    const float a1 = g1[h + 1] * rsqrtf(v1[h + 1] + EPS);
    const float pb0 = a0 * (b1[h] - m1[h]) + beta1[h];
    const float pb1 = a1 * (b1[h + 1] - m1[h + 1]) + beta1[h + 1];
    const float* We = W1 + 2048 * 512;
    float acc0[4], acc1[4];
    #pragma unroll
    for (int k = 0; k < 4; ++k) { acc0[k] = 0.f; acc1[k] = 0.f; }
    #pragma unroll 4
    for (int e = 0; e < 64; ++e) {
      float2 wv = *(const float2*)(We + e * 512 + h);
      #pragma unroll
      for (int k = 0; k < 4; ++k) {
        float ev = smem[k * 64 + e];  // LDS broadcast
        acc0[k] = fmaf(ev, wv.x, acc0[k]);
        acc1[k] = fmaf(ev, wv.y, acc1[k]);
      }
    }
    #pragma unroll
    for (int k = 0; k < 4; ++k) {
      // pbias folded into Q: h1 = Pf + (Q+pbias) - rep*R
      Q[(k0 + k) * 256 + t] = pack2(a0 * acc0[k] + pb0, a1 * acc1[k] + pb1);
      float2 wv = *(const float2*)(W1 + (size_t)(k0 + k) * 512 + h);
      R[(k0 + k) * 256 + t] = pack2(a0 * wv.x, a1 * wv.y);
    }
  } else if (x < 576) {
    const int h0 = (x - 512) * 8;
    const int o = t;
    unsigned d[4];
    #pragma unroll
    for (int i = 0; i < 4; ++i) {
      float v0 = W2[(h0 + 2 * i) * 256 + o];      // coalesced across o
      float v1_ = W2[(h0 + 2 * i + 1) * 256 + o];
      d[i] = pack2(v0, v1_);
    }
    *(uint4*)(W2t + o * 512 + h0) = make_uint4(d[0], d[1], d[2], d[3]);  // 16B/thread
  } else if (x < 704) {
    const int i = x - 576;
    const int b = i >> 1, half = i & 1;
    #pragma unroll
    for (int j = 0; j < 8; ++j) smem[j * 256 + t] = rep[b * 2048 + j * 256 + t];
    __syncthreads();
    const int h = half * 256 + t;
    const float ah = g1[h] * rsqrtf(v1[h] + EPS);
    float acc = 0.f;
    #pragma unroll 8
    for (int k = 0; k < 2048; ++k)
      acc = fmaf(smem[k], W1[(size_t)k * 512 + h], acc);  // coalesced 256B/wave
    Pf[b * 512 + h] = ah * acc;
  } else {
    float tv = g2[t] * rsqrtf(v2[t] + EPS);
    t2[t] = tv;
    c2[t] = tv * (b2[t] - m2[t]) + beta2[t];
  }
}

// ---------------- fused main (v4: K-chunk 128, 4 chunks, half the barriers) ----------------
// Block: 2 k-values x 64 b = 128 rows, N=256 (all o), K=512 in 4 chunks of 128.
// Wave w: o block [w*64,w*64+64); gen role: ks_g = w (which 32-col quarter of the chunk).
// A in LDS fragment-ordered: frag id = ((mi*4+ks)*4+lq)*16+ln, 16B each; buffer 32KB,
// double-buffered (68KB LDS total -> still 2 blocks/CU). acc[8][4]=128 AGPR + ~128 VGPR.
__global__ __launch_bounds__(256, 2) void fused_main(
    const float* __restrict__ rep,
    const float* __restrict__ Pf,
    const unsigned* __restrict__ Q,
    const unsigned* __restrict__ Rm,
    const unsigned short* __restrict__ W2t,
    const float* __restrict__ t2, const float* __restrict__ c2,
    const float* __restrict__ W3, const float* __restrict__ b3,
    float* __restrict__ out) {
  __shared__ unsigned short A_lds[2][16384];  // 2 x 32KB, fragment-ordered
  __shared__ float repc[128];
  __shared__ float partial[4][128];

  const int t = threadIdx.x;
  const int w = t >> 6;          // 0..3
  const int ln = t & 15;
  const int lq = (t >> 4) & 3;
  const int ks_g = w;            // gen role: 32-col quarter of the 128-chunk
  const int k0 = blockIdx.x * 2;

  if (t < 128) repc[t] = rep[(t & 63) * 2048 + k0 + (t >> 6)];

  f32x4 acc[8][4];
  #pragma unroll
  for (int mi = 0; mi < 8; ++mi)
    #pragma unroll
    for (int nj = 0; nj < 4; ++nj) acc[mi][nj] = (f32x4){0.f, 0.f, 0.f, 0.f};

  __syncthreads();  // repc visible

  // generate chunk c of A (128 rows x 128 cols) into buf, fragment-ordered
  auto gen = [&](int c, unsigned short* buf) {
    const int col = c * 128 + ks_g * 32 + lq * 8;
    const int cb2 = col >> 1;
    #pragma unroll
    for (int p = 0; p < 8; ++p) {
      const int mi = p;
      const int r = mi * 16 + ln;   // 0..127
      const int bb = r & 63;
      const int kg = k0 + (r >> 6);
      const float4 pv0 = *(const float4*)(Pf + bb * 512 + col);
      const float4 pv1 = *(const float4*)(Pf + bb * 512 + col + 4);
      const uint4 qv = *(const uint4*)(Q + (kg << 8) + cb2);
      const uint4 rv = *(const uint4*)(Rm + (kg << 8) + cb2);
      const float rb = repc[r];
      unsigned d[4];
      {
        float z0 = fmaf(-rb, bflo(rv.x), pv0.x + bflo(qv.x));
        float z1 = fmaf(-rb, bfhi(rv.x), pv0.y + bfhi(qv.x));
        d[0] = pack2(fmaxf(z0, 0.f), fmaxf(z1, 0.f));
        z0 = fmaf(-rb, bflo(rv.y), pv0.z + bflo(qv.y));
        z1 = fmaf(-rb, bfhi(rv.y), pv0.w + bfhi(qv.y));
        d[1] = pack2(fmaxf(z0, 0.f), fmaxf(z1, 0.f));
        z0 = fmaf(-rb, bflo(rv.z), pv1.x + bflo(qv.z));
        z1 = fmaf(-rb, bfhi(rv.z), pv1.y + bfhi(qv.z));
        d[2] = pack2(fmaxf(z0, 0.f), fmaxf(z1, 0.f));
        z0 = fmaf(-rb, bflo(rv.w), pv1.z + bflo(qv.w));
        z1 = fmaf(-rb, bfhi(rv.w), pv1.w + bfhi(qv.w));
        d[3] = pack2(fmaxf(z0, 0.f), fmaxf(z1, 0.f));
      }
      // fragment id = ((mi*4 + ks_g)*4 + lq)*16 + ln ; 16B per fragment
      *(uint4*)(&buf[(size_t)((((mi * 4 + ks_g) * 4 + lq) * 16 + ln)) * 8]) =
          make_uint4(d[0], d[1], d[2], d[3]);
    }
  };

  gen(0, A_lds[0]);

  for (int c = 0; c < 4; ++c) {
    __syncthreads();  // writes of buf[c&1] visible; prior reads of buf[(c+1)&1] done
    if (c < 3) gen(c + 1, A_lds[(c + 1) & 1]);
    const unsigned short* buf = A_lds[c & 1];
    #pragma unroll
    for (int ks = 0; ks < 4; ++ks) {
      short8 afr[8];
      #pragma unroll
      for (int mi = 0; mi < 8; ++mi)
        afr[mi] = *(const short8*)(buf + (size_t)((((mi * 4 + ks) * 4 + lq) * 16 + ln) * 8));
      short8 bfr[4];
      #pragma unroll
      for (int nj = 0; nj < 4; ++nj)
        bfr[nj] = *(const short8*)(W2t + (size_t)(w * 64 + nj * 16 + ln) * 512 + c * 128 + ks * 32 + lq * 8);
      #pragma unroll
      for (int mi = 0; mi < 8; ++mi)
        #pragma unroll
        for (int nj = 0; nj < 4; ++nj)
          acc[mi][nj] = __builtin_amdgcn_mfma_f32_16x16x32_bf16(afr[mi], bfr[nj], acc[mi][nj], 0, 0, 0);
    }
  }

  // epilogue: u = relu(t2[o]*acc + c2[o]) * W3[o]; reduce over o
  float t2v[4], c2v[4], w3v[4];
  #pragma unroll
  for (int nj = 0; nj < 4; ++nj) {
    int o = w * 64 + nj * 16 + ln;
    t2v[nj] = t2[o];
    c2v[nj] = c2[o];
    w3v[nj] = W3[o];
  }
  #pragma unroll
  for (int mi = 0; mi < 8; ++mi) {
    float s[4] = {0.f, 0.f, 0.f, 0.f};
    #pragma unroll
    for (int nj = 0; nj < 4; ++nj)
      #pragma unroll
      for (int r = 0; r < 4; ++r) {
        float u = fmaf(t2v[nj], acc[mi][nj][r], c2v[nj]);
        u = fmaxf(u, 0.f);
        s[r] = fmaf(u, w3v[nj], s[r]);
      }
    #pragma unroll
    for (int r = 0; r < 4; ++r) {
      #pragma unroll
      for (int m = 1; m < 16; m <<= 1) s[r] += __shfl_xor(s[r], m, 64);
    }
    if (ln == 0) {
      #pragma unroll
      for (int r = 0; r < 4; ++r) partial[w][mi * 16 + lq * 4 + r] = s[r];
    }
  }
  __syncthreads();
  if (t < 128) {
    out[(t & 63) * 2048 + k0 + (t >> 6)] =
        partial[0][t] + partial[1][t] + partial[2][t] + partial[3][t] + b3[0];
  }
}

extern "C" void kernel_launch(void* const* d_in, const int* in_sizes, int n_in,
                              void* d_out, int out_size, void* d_ws, size_t ws_size,
                              hipStream_t stream) {
  const float* rep   = (const float*)d_in[0];
  const float* emb   = (const float*)d_in[1];
  const float* W1    = (const float*)d_in[2];
  const float* b1    = (const float*)d_in[3];
  const float* g1    = (const float*)d_in[4];
  const float* beta1 = (const float*)d_in[5];
  const float* m1    = (const float*)d_in[6];
  const float* v1    = (const float*)d_in[7];
  const float* W2    = (const float*)d_in[8];
  const float* b2    = (const float*)d_in[9];
  const float* g2    = (const float*)d_in[10];
  const float* beta2 = (const float*)d_in[11];
  const float* m2    = (const float*)d_in[12];
  const float* v2    = (const float*)d_in[13];
  const float* W3    = (const float*)d_in[14];
  const float* b3    = (const float*)d_in[15];
  float* out = (float*)d_out;

  char* ws = (char*)d_ws;
  float* Pf            = (float*)(ws + 0);            // 64x512 f32   (128 KB)
  unsigned* Q          = (unsigned*)(ws + 131072);    // 2048x256 pairs (2 MB)
  unsigned* R          = (unsigned*)(ws + 2228224);   // 2048x256 pairs (2 MB)
  unsigned short* W2t  = (unsigned short*)(ws + 4325376);  // 256x512 bf16 (256 KB)
  float* t2            = (float*)(ws + 4587520);      // 256 f32
  float* c2            = (float*)(ws + 4588544);      // 256 f32

  prep2<<<705, 256, 0, stream>>>(rep, emb, W1, g1, v1, b1, m1, beta1, W2, g2, v2,
                                 b2, m2, beta2, Q, R, W2t, t2, c2, Pf);
  fused_main<<<1024, 256, 0, stream>>>(rep, Pf, Q, R, W2t, t2, c2, W3, b3, out);
}

// Round 6
// 226.685 us; speedup vs baseline: 1.2661x; 1.2661x over previous
//
#include <hip/hip_runtime.h>

#define EPS 1e-5f
// B=64, D=2048, E=64, H1=512, H2=256

typedef __attribute__((ext_vector_type(8))) short short8;
typedef __attribute__((ext_vector_type(4))) float f32x4;

__device__ __forceinline__ float bflo(unsigned u) { return __uint_as_float(u << 16); }
__device__ __forceinline__ float bfhi(unsigned u) { return __uint_as_float(u & 0xffff0000u); }
__device__ __forceinline__ unsigned short f2bf(float f) {
  unsigned u = __float_as_uint(f);
  u = u + 0x7FFFu + ((u >> 16) & 1u);  // RNE
  return (unsigned short)(u >> 16);
}
__device__ __forceinline__ unsigned pack2(float a, float b) {
  return (unsigned)f2bf(a) | ((unsigned)f2bf(b) << 16);
}
__device__ __forceinline__ void g2lds16(const void* g, void* l) {
  __builtin_amdgcn_global_load_lds(
      (const __attribute__((address_space(1))) unsigned*)g,
      (__attribute__((address_space(3))) unsigned*)l, 16, 0, 0);
}

// ======================= MAIN PATH =======================

// ---------------- prep2: Q(+pbias), R, W2t, t2/c2, Pf-zero ----------------
__global__ __launch_bounds__(256) void prep2(
    const float* __restrict__ emb, const float* __restrict__ W1,
    const float* __restrict__ g1, const float* __restrict__ v1,
    const float* __restrict__ b1, const float* __restrict__ m1,
    const float* __restrict__ beta1,
    const float* __restrict__ W2,
    const float* __restrict__ g2, const float* __restrict__ v2,
    const float* __restrict__ b2, const float* __restrict__ m2,
    const float* __restrict__ beta2,
    unsigned* __restrict__ Q, unsigned* __restrict__ R,
    unsigned short* __restrict__ W2t,
    float* __restrict__ t2, float* __restrict__ c2, float* __restrict__ Pf) {
  __shared__ float smem[256];
  const int x = blockIdx.x, t = threadIdx.x;
  if (x < 512) {
    const int k0 = x * 4;
    smem[t] = emb[x * 256 + t];  // 4 emb rows, coalesced
    __syncthreads();
    const int h = t * 2;
    const float a0 = g1[h] * rsqrtf(v1[h] + EPS);
    const float a1 = g1[h + 1] * rsqrtf(v1[h + 1] + EPS);
    const float pb0 = a0 * (b1[h] - m1[h]) + beta1[h];
    const float pb1 = a1 * (b1[h + 1] - m1[h + 1]) + beta1[h + 1];
    const float* We = W1 + 2048 * 512;
    float acc0[4], acc1[4];
    #pragma unroll
    for (int k = 0; k < 4; ++k) { acc0[k] = 0.f; acc1[k] = 0.f; }
    #pragma unroll 4
    for (int e = 0; e < 64; ++e) {
      float2 wv = *(const float2*)(We + e * 512 + h);
      #pragma unroll
      for (int k = 0; k < 4; ++k) {
        float ev = smem[k * 64 + e];  // LDS broadcast
        acc0[k] = fmaf(ev, wv.x, acc0[k]);
        acc1[k] = fmaf(ev, wv.y, acc1[k]);
      }
    }
    #pragma unroll
    for (int k = 0; k < 4; ++k) {
      // pbias folded into Q: h1bn = Pf + (Q+pbias) - rep*R
      Q[(k0 + k) * 256 + t] = pack2(a0 * acc0[k] + pb0, a1 * acc1[k] + pb1);
      float2 wv = *(const float2*)(W1 + (size_t)(k0 + k) * 512 + h);
      R[(k0 + k) * 256 + t] = pack2(a0 * wv.x, a1 * wv.y);
    }
  } else if (x < 576) {
    const int h0 = (x - 512) * 8;
    const int o = t;
    unsigned d[4];
    #pragma unroll
    for (int i = 0; i < 4; ++i) {
      float v0 = W2[(h0 + 2 * i) * 256 + o];      // coalesced across o
      float v1_ = W2[(h0 + 2 * i + 1) * 256 + o];
      d[i] = pack2(v0, v1_);
    }
    *(uint4*)(W2t + o * 512 + h0) = make_uint4(d[0], d[1], d[2], d[3]);  // 16B/thread
  } else {
    float tv = g2[t] * rsqrtf(v2[t] + EPS);
    t2[t] = tv;
    c2[t] = tv * (b2[t] - m2[t]) + beta2[t];
    f32x4 z = (f32x4){0.f, 0.f, 0.f, 0.f};
    #pragma unroll 8
    for (int j = 0; j < 32; ++j)
      *(f32x4*)(Pf + ((size_t)(j * 256 + t)) * 4) = z;  // zero 64x512 f32
  }
}

// ---------------- p_gemm: Pf += rep @ R (split-K, atomic f32) — R3-proven ----------------
__global__ __launch_bounds__(256) void p_gemm(
    const float* __restrict__ rep, const unsigned* __restrict__ R,
    float* __restrict__ Pf) {
  __shared__ float red[4][512];
  const int b = blockIdx.x >> 3, ksl = blockIdx.x & 7;
  const int t = threadIdx.x, lane = t & 63, kq = t >> 6;
  const int kbase = ksl * 256 + kq * 64;
  const unsigned* Rp = R + (size_t)kbase * 256 + lane * 4;
  const float* rp = rep + b * 2048 + kbase;
  float acc[8];
  #pragma unroll
  for (int i = 0; i < 8; ++i) acc[i] = 0.f;
  #pragma unroll 8
  for (int k = 0; k < 64; ++k) {
    uint4 rv = *(const uint4*)(Rp + (size_t)k * 256);
    float rk = rp[k];  // wave-uniform scalar
    acc[0] = fmaf(rk, bflo(rv.x), acc[0]); acc[1] = fmaf(rk, bfhi(rv.x), acc[1]);
    acc[2] = fmaf(rk, bflo(rv.y), acc[2]); acc[3] = fmaf(rk, bfhi(rv.y), acc[3]);
    acc[4] = fmaf(rk, bflo(rv.z), acc[4]); acc[5] = fmaf(rk, bfhi(rv.z), acc[5]);
    acc[6] = fmaf(rk, bflo(rv.w), acc[6]); acc[7] = fmaf(rk, bfhi(rv.w), acc[7]);
  }
  *(f32x4*)(&red[kq][lane * 8])     = (f32x4){acc[0], acc[1], acc[2], acc[3]};
  *(f32x4*)(&red[kq][lane * 8 + 4]) = (f32x4){acc[4], acc[5], acc[6], acc[7]};
  __syncthreads();
  {
    const int h = t * 2;
    float s0 = red[0][h] + red[1][h] + red[2][h] + red[3][h];
    float s1 = red[0][h + 1] + red[1][h + 1] + red[2][h + 1] + red[3][h + 1];
    atomicAdd(&Pf[b * 512 + h], s0);
    atomicAdd(&Pf[b * 512 + h + 1], s1);
  }
}

// ---------------- genA: A = bf16(relu(Pf + Q - rep*R)), fragment-ordered ----------------
// grid 1024 (k-pairs) x 256 thr. No barriers, no LDS, low regs -> high occupancy.
// A layout: [kp][c][frag-group (p*256+t)][8 shorts]; 16B coalesced stores.
__global__ __launch_bounds__(256) void genA(
    const float* __restrict__ rep, const float* __restrict__ Pf,
    const unsigned* __restrict__ Q, const unsigned* __restrict__ Rm,
    unsigned* __restrict__ A) {
  const int t = threadIdx.x;
  const int kp = blockIdx.x;
  const int w = t >> 6, ln = t & 15, lq = (t >> 4) & 3;
  const int ks_id = w & 1, hi_id = w >> 1;
  const int k0 = kp * 2;
  float rb[4];
  #pragma unroll
  for (int p = 0; p < 4; ++p) {
    int r = (p * 2 + hi_id) * 16 + ln;
    rb[p] = rep[(r & 63) * 2048 + k0 + (r >> 6)];
  }
  unsigned* Ab = A + (size_t)kp * 32768;  // 32768 unsigned per k-pair block
  #pragma unroll 1
  for (int c = 0; c < 8; ++c) {
    const int col = c * 64 + ks_id * 32 + lq * 8;
    const int cb2 = col >> 1;
    #pragma unroll
    for (int p = 0; p < 4; ++p) {
      const int r = (p * 2 + hi_id) * 16 + ln;
      const int bb = r & 63;
      const int kg = k0 + (r >> 6);
      const float4 pv0 = *(const float4*)(Pf + bb * 512 + col);
      const float4 pv1 = *(const float4*)(Pf + bb * 512 + col + 4);
      const uint4 qv = *(const uint4*)(Q + (kg << 8) + cb2);
      const uint4 rv = *(const uint4*)(Rm + (kg << 8) + cb2);
      const float rp_ = rb[p];
      unsigned d[4];
      float z0, z1;
      z0 = fmaf(-rp_, bflo(rv.x), pv0.x + bflo(qv.x));
      z1 = fmaf(-rp_, bfhi(rv.x), pv0.y + bfhi(qv.x));
      d[0] = pack2(fmaxf(z0, 0.f), fmaxf(z1, 0.f));
      z0 = fmaf(-rp_, bflo(rv.y), pv0.z + bflo(qv.y));
      z1 = fmaf(-rp_, bfhi(rv.y), pv0.w + bfhi(qv.y));
      d[1] = pack2(fmaxf(z0, 0.f), fmaxf(z1, 0.f));
      z0 = fmaf(-rp_, bflo(rv.z), pv1.x + bflo(qv.z));
      z1 = fmaf(-rp_, bfhi(rv.z), pv1.y + bfhi(qv.z));
      d[2] = pack2(fmaxf(z0, 0.f), fmaxf(z1, 0.f));
      z0 = fmaf(-rp_, bflo(rv.w), pv1.z + bflo(qv.w));
      z1 = fmaf(-rp_, bfhi(rv.w), pv1.w + bfhi(qv.w));
      d[3] = pack2(fmaxf(z0, 0.f), fmaxf(z1, 0.f));
      *(uint4*)(Ab + (size_t)(c * 1024 + p * 256 + t) * 4) =
          make_uint4(d[0], d[1], d[2], d[3]);
    }
  }
}

// ---------------- gemmA: pure GEMM, A staged via global_load_lds ----------------
// Block = k-pair (128 rows) x 256 o, K=512 in 8 chunks of 64. Wave w: o block w*64.
// Chunk c+1 DMA issued right after barrier -> lands under MFMA(c) (m97 pattern).
__global__ __launch_bounds__(256, 2) void gemmA(
    const unsigned* __restrict__ A,
    const unsigned short* __restrict__ W2t,
    const float* __restrict__ t2, const float* __restrict__ c2,
    const float* __restrict__ W3, const float* __restrict__ b3,
    float* __restrict__ out) {
  __shared__ unsigned short A_lds[2][8192];  // 2 x 16KB, fragment-ordered
  __shared__ float partial[4][128];
  const int t = threadIdx.x;
  const int w = t >> 6, ln = t & 15, lq = (t >> 4) & 3;
  const int l = t & 63;
  const int kp = blockIdx.x, k0 = kp * 2;
  const unsigned* Ab = A + (size_t)kp * 32768;

  f32x4 acc[8][4];
  #pragma unroll
  for (int mi = 0; mi < 8; ++mi)
    #pragma unroll
    for (int nj = 0; nj < 4; ++nj) acc[mi][nj] = (f32x4){0.f, 0.f, 0.f, 0.f};

  auto stage = [&](int c, int bi) {
    // wave w copies its 4KB quarter: 4 issues of 1KB (64 lanes x 16B), linear
    const unsigned* src = Ab + (size_t)c * 4096 + (w * 64 + l) * 4;
    #pragma unroll
    for (int i = 0; i < 4; ++i)
      g2lds16(src + i * 1024, &A_lds[bi][(size_t)(i * 256 + w * 64) * 8]);
  };

  stage(0, 0);

  for (int c = 0; c < 8; ++c) {
    __syncthreads();  // drains DMA(c) (vmcnt0) + all waves arrived
    if (c < 7) stage(c + 1, (c + 1) & 1);  // in flight under MFMA(c)
    const unsigned short* buf = A_lds[c & 1];
    #pragma unroll
    for (int ks = 0; ks < 2; ++ks) {
      short8 afr[8];
      #pragma unroll
      for (int mi = 0; mi < 8; ++mi)
        afr[mi] = *(const short8*)(buf + (size_t)((((mi * 2 + ks) * 4 + lq) * 16 + ln) * 8));
      short8 bfr[4];
      #pragma unroll
      for (int nj = 0; nj < 4; ++nj)
        bfr[nj] = *(const short8*)(W2t + (size_t)(w * 64 + nj * 16 + ln) * 512 + c * 64 + ks * 32 + lq * 8);
      #pragma unroll
      for (int mi = 0; mi < 8; ++mi)
        #pragma unroll
        for (int nj = 0; nj < 4; ++nj)
          acc[mi][nj] = __builtin_amdgcn_mfma_f32_16x16x32_bf16(afr[mi], bfr[nj], acc[mi][nj], 0, 0, 0);
    }
  }

  // epilogue: u = relu(t2[o]*acc + c2[o]) * W3[o]; reduce over o
  float t2v[4], c2v[4], w3v[4];
  #pragma unroll
  for (int nj = 0; nj < 4; ++nj) {
    int o = w * 64 + nj * 16 + ln;
    t2v[nj] = t2[o];
    c2v[nj] = c2[o];
    w3v[nj] = W3[o];
  }
  #pragma unroll
  for (int mi = 0; mi < 8; ++mi) {
    float s[4] = {0.f, 0.f, 0.f, 0.f};
    #pragma unroll
    for (int nj = 0; nj < 4; ++nj)
      #pragma unroll
      for (int r = 0; r < 4; ++r) {
        float u = fmaf(t2v[nj], acc[mi][nj][r], c2v[nj]);
        u = fmaxf(u, 0.f);
        s[r] = fmaf(u, w3v[nj], s[r]);
      }
    #pragma unroll
    for (int r = 0; r < 4; ++r) {
      #pragma unroll
      for (int m = 1; m < 16; m <<= 1) s[r] += __shfl_xor(s[r], m, 64);
    }
    if (ln == 0) {
      #pragma unroll
      for (int r = 0; r < 4; ++r) partial[w][mi * 16 + lq * 4 + r] = s[r];
    }
  }
  __syncthreads();
  if (t < 128) {
    out[(t & 63) * 2048 + k0 + (t >> 6)] =
        partial[0][t] + partial[1][t] + partial[2][t] + partial[3][t] + b3[0];
  }
}

// ======================= FALLBACK PATH (R1 verbatim, proven 194.7us) =======================
__global__ __launch_bounds__(256) void prep_v1(
    const float* __restrict__ emb, const float* __restrict__ W1,
    const float* __restrict__ g1, const float* __restrict__ v1,
    const float* __restrict__ b1, const float* __restrict__ m1,
    const float* __restrict__ beta1,
    const float* __restrict__ W2,
    const float* __restrict__ g2, const float* __restrict__ v2,
    const float* __restrict__ b2, const float* __restrict__ m2,
    const float* __restrict__ beta2,
    unsigned* __restrict__ Q, unsigned* __restrict__ R,
    unsigned short* __restrict__ W2t,
    float* __restrict__ t2, float* __restrict__ c2, float* __restrict__ pbias) {
  const int x = blockIdx.x, t = threadIdx.x;
  if (x < 256) {
    const int k0 = x * 8;
    const int h = t * 2;
    const float a0 = g1[h] * rsqrtf(v1[h] + EPS);
    const float a1 = g1[h + 1] * rsqrtf(v1[h + 1] + EPS);
    const float* We = W1 + 2048 * 512;
    float acc0[8], acc1[8];
    #pragma unroll
    for (int k = 0; k < 8; ++k) { acc0[k] = 0.f; acc1[k] = 0.f; }
    for (int e = 0; e < 64; ++e) {
      float2 wv = *(const float2*)(We + e * 512 + h);
      #pragma unroll
      for (int k = 0; k < 8; ++k) {
        float ev = emb[(k0 + k) * 64 + e];
        acc0[k] = fmaf(ev, wv.x, acc0[k]);
        acc1[k] = fmaf(ev, wv.y, acc1[k]);
      }
    }
    #pragma unroll
    for (int k = 0; k < 8; ++k) {
      Q[(k0 + k) * 256 + t] = pack2(a0 * acc0[k], a1 * acc1[k]);
      float2 wv = *(const float2*)(W1 + (size_t)(k0 + k) * 512 + h);
      R[(k0 + k) * 256 + t] = pack2(a0 * wv.x, a1 * wv.y);
    }
  } else if (x < 320) {
    const int h0 = (x - 256) * 8;
    const int o = t;
    unsigned d[4];
    #pragma unroll
    for (int i = 0; i < 4; ++i) {
      float v0 = W2[(h0 + 2 * i) * 256 + o];
      float v1_ = W2[(h0 + 2 * i + 1) * 256 + o];
      d[i] = pack2(v0, v1_);
    }
    *(uint4*)(W2t + o * 512 + h0) = make_uint4(d[0], d[1], d[2], d[3]);
  } else {
    float tv = g2[t] * rsqrtf(v2[t] + EPS);
    t2[t] = tv;
    c2[t] = tv * (b2[t] - m2[t]) + beta2[t];
    #pragma unroll
    for (int i = 0; i < 2; ++i) {
      int h = t + i * 256;
      float a = g1[h] * rsqrtf(v1[h] + EPS);
      pbias[h] = a * (b1[h] - m1[h]) + beta1[h];
    }
  }
}

__global__ __launch_bounds__(1024) void p_gemm_v1(
    const float* __restrict__ rep, const unsigned* __restrict__ R,
    const float* __restrict__ pbias, unsigned* __restrict__ P) {
  __shared__ float red[16 * 512];
  const int b = blockIdx.x, t = threadIdx.x;
  const int lane = t & 63, kq = t >> 6;
  const int hl = lane * 8;
  const float* rp = rep + b * 2048 + kq * 128;
  const unsigned* Rp = R + (size_t)(kq * 128) * 256 + lane * 4;
  float acc[8];
  #pragma unroll
  for (int i = 0; i < 8; ++i) acc[i] = 0.f;
  #pragma unroll 4
  for (int k = 0; k < 128; ++k) {
    uint4 rv = *(const uint4*)(Rp + (size_t)k * 256);
    float rk = rp[k];
    acc[0] = fmaf(rk, bflo(rv.x), acc[0]); acc[1] = fmaf(rk, bfhi(rv.x), acc[1]);
    acc[2] = fmaf(rk, bflo(rv.y), acc[2]); acc[3] = fmaf(rk, bfhi(rv.y), acc[3]);
    acc[4] = fmaf(rk, bflo(rv.z), acc[4]); acc[5] = fmaf(rk, bfhi(rv.z), acc[5]);
    acc[6] = fmaf(rk, bflo(rv.w), acc[6]); acc[7] = fmaf(rk, bfhi(rv.w), acc[7]);
  }
  *(f32x4*)(&red[kq * 512 + hl])     = (f32x4){acc[0], acc[1], acc[2], acc[3]};
  *(f32x4*)(&red[kq * 512 + hl + 4]) = (f32x4){acc[4], acc[5], acc[6], acc[7]};
  __syncthreads();
  if (t < 256) {
    const int h = t * 2;
    float s0 = 0.f, s1 = 0.f;
    #pragma unroll
    for (int q = 0; q < 16; ++q) { s0 += red[q * 512 + h]; s1 += red[q * 512 + h + 1]; }
    P[b * 256 + t] = pack2(s0 + pbias[h], s1 + pbias[h + 1]);
  }
}

__global__ __launch_bounds__(256, 2) void fused_main_v1(
    const float* __restrict__ rep,
    const unsigned* __restrict__ P,
    const unsigned* __restrict__ Q,
    const unsigned* __restrict__ Rm,
    const unsigned short* __restrict__ W2t,
    const float* __restrict__ t2, const float* __restrict__ c2,
    const float* __restrict__ W3, const float* __restrict__ b3,
    float* __restrict__ out) {
  __shared__ unsigned short A_lds[2][8192];
  __shared__ float repc[128];
  __shared__ float partial[4][128];
  const int t = threadIdx.x;
  const int w = t >> 6;
  const int ln = t & 15;
  const int lq = (t >> 4) & 3;
  const int ks_id = w & 1;
  const int hi_id = w >> 1;
  const int k0 = blockIdx.x * 2;
  if (t < 128) repc[t] = rep[(t & 63) * 2048 + k0 + (t >> 6)];
  f32x4 acc[8][4];
  #pragma unroll
  for (int mi = 0; mi < 8; ++mi)
    #pragma unroll
    for (int nj = 0; nj < 4; ++nj) acc[mi][nj] = (f32x4){0.f, 0.f, 0.f, 0.f};
  __syncthreads();
  auto gen = [&](int c, unsigned short* buf) {
    const int colbase = c * 64 + ks_id * 32 + lq * 8;
    const int cb2 = colbase >> 1;
    #pragma unroll
    for (int p = 0; p < 4; ++p) {
      const int mi = p * 2 + hi_id;
      const int r = mi * 16 + ln;
      const int bb = r & 63;
      const int kg = k0 + (r >> 6);
      uint4 pv = *(const uint4*)(P + (bb << 8) + cb2);
      uint4 qv = *(const uint4*)(Q + (kg << 8) + cb2);
      uint4 rv = *(const uint4*)(Rm + (kg << 8) + cb2);
      const float rb = repc[r];
      unsigned d[4];
      {
        float z0 = fmaf(-rb, bflo(rv.x), bflo(pv.x) + bflo(qv.x));
        float z1 = fmaf(-rb, bfhi(rv.x), bfhi(pv.x) + bfhi(qv.x));
        d[0] = pack2(fmaxf(z0, 0.f), fmaxf(z1, 0.f));
        z0 = fmaf(-rb, bflo(rv.y), bflo(pv.y) + bflo(qv.y));
        z1 = fmaf(-rb, bfhi(rv.y), bfhi(pv.y) + bfhi(qv.y));
        d[1] = pack2(fmaxf(z0, 0.f), fmaxf(z1, 0.f));
        z0 = fmaf(-rb, bflo(rv.z), bflo(pv.z) + bflo(qv.z));
        z1 = fmaf(-rb, bfhi(rv.z), bfhi(pv.z) + bfhi(qv.z));
        d[2] = pack2(fmaxf(z0, 0.f), fmaxf(z1, 0.f));
        z0 = fmaf(-rb, bflo(rv.w), bflo(pv.w) + bflo(qv.w));
        z1 = fmaf(-rb, bfhi(rv.w), bfhi(pv.w) + bfhi(qv.w));
        d[3] = pack2(fmaxf(z0, 0.f), fmaxf(z1, 0.f));
      }
      *(uint4*)(&buf[(size_t)(p * 256 + t) * 8]) = make_uint4(d[0], d[1], d[2], d[3]);
    }
  };
  gen(0, A_lds[0]);
  for (int c = 0; c < 8; ++c) {
    __syncthreads();
    if (c < 7) gen(c + 1, A_lds[(c + 1) & 1]);
    const unsigned short* buf = A_lds[c & 1];
    #pragma unroll
    for (int ks = 0; ks < 2; ++ks) {
      short8 afr[8];
      #pragma unroll
      for (int mi = 0; mi < 8; ++mi)
        afr[mi] = *(const short8*)(buf + (size_t)((((mi * 2 + ks) * 4 + lq) * 16 + ln) * 8));
      short8 bfr[4];
      #pragma unroll
      for (int nj = 0; nj < 4; ++nj)
        bfr[nj] = *(const short8*)(W2t + (size_t)(w * 64 + nj * 16 + ln) * 512 + c * 64 + ks * 32 + lq * 8);
      #pragma unroll
      for (int mi = 0; mi < 8; ++mi)
        #pragma unroll
        for (int nj = 0; nj < 4; ++nj)
          acc[mi][nj] = __builtin_amdgcn_mfma_f32_16x16x32_bf16(afr[mi], bfr[nj], acc[mi][nj], 0, 0, 0);
    }
  }
  float t2v[4], c2v[4], w3v[4];
  #pragma unroll
  for (int nj = 0; nj < 4; ++nj) {
    int o = w * 64 + nj * 16 + ln;
    t2v[nj] = t2[o];
    c2v[nj] = c2[o];
    w3v[nj] = W3[o];
  }
  #pragma unroll
  for (int mi = 0; mi < 8; ++mi) {
    float s[4] = {0.f, 0.f, 0.f, 0.f};
    #pragma unroll
    for (int nj = 0; nj < 4; ++nj)
      #pragma unroll
      for (int r = 0; r < 4; ++r) {
        float u = fmaf(t2v[nj], acc[mi][nj][r], c2v[nj]);
        u = fmaxf(u, 0.f);
        s[r] = fmaf(u, w3v[nj], s[r]);
      }
    #pragma unroll
    for (int r = 0; r < 4; ++r) {
      #pragma unroll
      for (int m = 1; m < 16; m <<= 1) s[r] += __shfl_xor(s[r], m, 64);
    }
    if (ln == 0) {
      #pragma unroll
      for (int r = 0; r < 4; ++r) partial[w][mi * 16 + lq * 4 + r] = s[r];
    }
  }
  __syncthreads();
  if (t < 128) {
    out[(t & 63) * 2048 + k0 + (t >> 6)] =
        partial[0][t] + partial[1][t] + partial[2][t] + partial[3][t] + b3[0];
  }
}

extern "C" void kernel_launch(void* const* d_in, const int* in_sizes, int n_in,
                              void* d_out, int out_size, void* d_ws, size_t ws_size,
                              hipStream_t stream) {
  const float* rep   = (const float*)d_in[0];
  const float* emb   = (const float*)d_in[1];
  const float* W1    = (const float*)d_in[2];
  const float* b1    = (const float*)d_in[3];
  const float* g1    = (const float*)d_in[4];
  const float* beta1 = (const float*)d_in[5];
  const float* m1    = (const float*)d_in[6];
  const float* v1    = (const float*)d_in[7];
  const float* W2    = (const float*)d_in[8];
  const float* b2    = (const float*)d_in[9];
  const float* g2    = (const float*)d_in[10];
  const float* beta2 = (const float*)d_in[11];
  const float* m2    = (const float*)d_in[12];
  const float* v2    = (const float*)d_in[13];
  const float* W3    = (const float*)d_in[14];
  const float* b3    = (const float*)d_in[15];
  float* out = (float*)d_out;
  char* ws = (char*)d_ws;

  const size_t A_OFF = 4589568;
  const size_t NEED = A_OFF + (size_t)134217728;  // A: 1024 kp x 64KB bf16

  if (ws_size >= NEED) {
    float* Pf            = (float*)(ws + 0);           // 64x512 f32 (128 KB)
    unsigned* Q          = (unsigned*)(ws + 131072);   // 2048x256 pairs (2 MB)
    unsigned* R          = (unsigned*)(ws + 2228224);  // 2048x256 pairs (2 MB)
    unsigned short* W2t  = (unsigned short*)(ws + 4325376);  // 256x512 bf16
    float* t2            = (float*)(ws + 4587520);
    float* c2            = (float*)(ws + 4588544);
    unsigned* A          = (unsigned*)(ws + A_OFF);    // 128 MB

    prep2<<<577, 256, 0, stream>>>(emb, W1, g1, v1, b1, m1, beta1, W2, g2, v2,
                                   b2, m2, beta2, Q, R, W2t, t2, c2, Pf);
    p_gemm<<<512, 256, 0, stream>>>(rep, R, Pf);
    genA<<<1024, 256, 0, stream>>>(rep, Pf, Q, R, A);
    gemmA<<<1024, 256, 0, stream>>>(A, W2t, t2, c2, W3, b3, out);
  } else {
    float* t2            = (float*)(ws + 0);
    float* c2            = (float*)(ws + 1024);
    float* pbias         = (float*)(ws + 2048);
    unsigned* P          = (unsigned*)(ws + 4096);
    unsigned* Q          = (unsigned*)(ws + 69632);
    unsigned* R          = (unsigned*)(ws + 2166784);
    unsigned short* W2t  = (unsigned short*)(ws + 4263936);

    prep_v1<<<321, 256, 0, stream>>>(emb, W1, g1, v1, b1, m1, beta1, W2, g2, v2,
                                     b2, m2, beta2, Q, R, W2t, t2, c2, pbias);
    p_gemm_v1<<<64, 1024, 0, stream>>>(rep, R, pbias, P);
    fused_main_v1<<<1024, 256, 0, stream>>>(rep, P, Q, R, W2t, t2, c2, W3, b3, out);
  }
}

// Round 7
// 182.583 us; speedup vs baseline: 1.5719x; 1.2415x over previous
//
#include <hip/hip_runtime.h>

#define EPS 1e-5f
// B=64, D=2048, E=64, H1=512, H2=256

typedef __attribute__((ext_vector_type(8))) short short8;
typedef __attribute__((ext_vector_type(4))) float f32x4;

__device__ __forceinline__ float bflo(unsigned u) { return __uint_as_float(u << 16); }
__device__ __forceinline__ float bfhi(unsigned u) { return __uint_as_float(u & 0xffff0000u); }
__device__ __forceinline__ unsigned short f2bf(float f) {
  unsigned u = __float_as_uint(f);
  u = u + 0x7FFFu + ((u >> 16) & 1u);  // RNE
  return (unsigned short)(u >> 16);
}
__device__ __forceinline__ unsigned pack2(float a, float b) {
  return (unsigned)f2bf(a) | ((unsigned)f2bf(b) << 16);
}

// ---------------- prep2: Q(+pbias), R, W2t, t2/c2, Pf-zero (R6-proven) ----------------
__global__ __launch_bounds__(256) void prep2(
    const float* __restrict__ emb, const float* __restrict__ W1,
    const float* __restrict__ g1, const float* __restrict__ v1,
    const float* __restrict__ b1, const float* __restrict__ m1,
    const float* __restrict__ beta1,
    const float* __restrict__ W2,
    const float* __restrict__ g2, const float* __restrict__ v2,
    const float* __restrict__ b2, const float* __restrict__ m2,
    const float* __restrict__ beta2,
    unsigned* __restrict__ Q, unsigned* __restrict__ R,
    unsigned short* __restrict__ W2t,
    float* __restrict__ t2, float* __restrict__ c2, float* __restrict__ Pf) {
  __shared__ float smem[256];
  const int x = blockIdx.x, t = threadIdx.x;
  if (x < 512) {
    const int k0 = x * 4;
    smem[t] = emb[x * 256 + t];  // 4 emb rows, coalesced
    __syncthreads();
    const int h = t * 2;
    const float a0 = g1[h] * rsqrtf(v1[h] + EPS);
    const float a1 = g1[h + 1] * rsqrtf(v1[h + 1] + EPS);
    const float pb0 = a0 * (b1[h] - m1[h]) + beta1[h];
    const float pb1 = a1 * (b1[h + 1] - m1[h + 1]) + beta1[h + 1];
    const float* We = W1 + 2048 * 512;
    float acc0[4], acc1[4];
    #pragma unroll
    for (int k = 0; k < 4; ++k) { acc0[k] = 0.f; acc1[k] = 0.f; }
    #pragma unroll 4
    for (int e = 0; e < 64; ++e) {
      float2 wv = *(const float2*)(We + e * 512 + h);
      #pragma unroll
      for (int k = 0; k < 4; ++k) {
        float ev = smem[k * 64 + e];  // LDS broadcast
        acc0[k] = fmaf(ev, wv.x, acc0[k]);
        acc1[k] = fmaf(ev, wv.y, acc1[k]);
      }
    }
    #pragma unroll
    for (int k = 0; k < 4; ++k) {
      // pbias folded into Q: h1bn = Pf + (Q+pbias) - rep*R
      Q[(k0 + k) * 256 + t] = pack2(a0 * acc0[k] + pb0, a1 * acc1[k] + pb1);
      float2 wv = *(const float2*)(W1 + (size_t)(k0 + k) * 512 + h);
      R[(k0 + k) * 256 + t] = pack2(a0 * wv.x, a1 * wv.y);
    }
  } else if (x < 576) {
    const int h0 = (x - 512) * 8;
    const int o = t;
    unsigned d[4];
    #pragma unroll
    for (int i = 0; i < 4; ++i) {
      float v0 = W2[(h0 + 2 * i) * 256 + o];      // coalesced across o
      float v1_ = W2[(h0 + 2 * i + 1) * 256 + o];
      d[i] = pack2(v0, v1_);
    }
    *(uint4*)(W2t + o * 512 + h0) = make_uint4(d[0], d[1], d[2], d[3]);  // 16B/thread
  } else {
    float tv = g2[t] * rsqrtf(v2[t] + EPS);
    t2[t] = tv;
    c2[t] = tv * (b2[t] - m2[t]) + beta2[t];
    f32x4 z = (f32x4){0.f, 0.f, 0.f, 0.f};
    #pragma unroll 8
    for (int j = 0; j < 32; ++j)
      *(f32x4*)(Pf + ((size_t)(j * 256 + t)) * 4) = z;  // zero 64x512 f32
  }
}

// ---------------- p_gemm: Pf += rep @ R (split-K, atomic f32) — R3/R6-proven ----------------
__global__ __launch_bounds__(256) void p_gemm(
    const float* __restrict__ rep, const unsigned* __restrict__ R,
    float* __restrict__ Pf) {
  __shared__ float red[4][512];
  const int b = blockIdx.x >> 3, ksl = blockIdx.x & 7;
  const int t = threadIdx.x, lane = t & 63, kq = t >> 6;
  const int kbase = ksl * 256 + kq * 64;
  const unsigned* Rp = R + (size_t)kbase * 256 + lane * 4;
  const float* rp = rep + b * 2048 + kbase;
  float acc[8];
  #pragma unroll
  for (int i = 0; i < 8; ++i) acc[i] = 0.f;
  #pragma unroll 8
  for (int k = 0; k < 64; ++k) {
    uint4 rv = *(const uint4*)(Rp + (size_t)k * 256);
    float rk = rp[k];  // wave-uniform scalar
    acc[0] = fmaf(rk, bflo(rv.x), acc[0]); acc[1] = fmaf(rk, bfhi(rv.x), acc[1]);
    acc[2] = fmaf(rk, bflo(rv.y), acc[2]); acc[3] = fmaf(rk, bfhi(rv.y), acc[3]);
    acc[4] = fmaf(rk, bflo(rv.z), acc[4]); acc[5] = fmaf(rk, bfhi(rv.z), acc[5]);
    acc[6] = fmaf(rk, bflo(rv.w), acc[6]); acc[7] = fmaf(rk, bfhi(rv.w), acc[7]);
  }
  *(f32x4*)(&red[kq][lane * 8])     = (f32x4){acc[0], acc[1], acc[2], acc[3]};
  *(f32x4*)(&red[kq][lane * 8 + 4]) = (f32x4){acc[4], acc[5], acc[6], acc[7]};
  __syncthreads();
  {
    const int h = t * 2;
    float s0 = red[0][h] + red[1][h] + red[2][h] + red[3][h];
    float s1 = red[0][h + 1] + red[1][h + 1] + red[2][h + 1] + red[3][h + 1];
    atomicAdd(&Pf[b * 512 + h], s0);
    atomicAdd(&Pf[b * 512 + h + 1], s1);
  }
}

// ---------------- fused main (v5: T14 split — load-early / pack+write-late) ----------------
// Block: 2 k x 64 b = 128 rows, N=256, K=512 in 8 chunks of 64. 4 waves, wave o-tile 64.
// Per chunk: barrier -> issue gen loads(c+1,half0) -> MFMA(c,ks0) [covers L2 latency]
//   -> pack+LDS-write half0 -> issue loads(c+1,half1) -> MFMA(c,ks1) -> pack+write half1.
// ds_writes now FOLLOW the MFMA ds_reads (no alias-order chain); staging split in
// halves keeps live regs ~220 (<256, no spill — R2 lesson).
__global__ __launch_bounds__(256, 2) void fused_main(
    const float* __restrict__ rep,
    const float* __restrict__ Pf,
    const unsigned* __restrict__ Q,
    const unsigned* __restrict__ Rm,
    const unsigned short* __restrict__ W2t,
    const float* __restrict__ t2, const float* __restrict__ c2,
    const float* __restrict__ W3, const float* __restrict__ b3,
    float* __restrict__ out) {
  __shared__ unsigned short A_lds[2][8192];  // 2 x 16KB, fragment-ordered
  __shared__ float partial[4][128];

  const int t = threadIdx.x;
  const int w = t >> 6;
  const int ln = t & 15;
  const int lq = (t >> 4) & 3;
  const int ks_id = w & 1;   // gen role: 32-col half of 64-chunk
  const int hi_id = w >> 1;  // gen role: mi parity
  const int k0 = blockIdx.x * 2;

  // rep scalars for this thread's 4 generated rows (regs, no LDS)
  float rb[4];
  #pragma unroll
  for (int p = 0; p < 4; ++p) {
    int r = (p * 2 + hi_id) * 16 + ln;
    rb[p] = rep[(r & 63) * 2048 + k0 + (r >> 6)];
  }

  f32x4 acc[8][4];
  #pragma unroll
  for (int mi = 0; mi < 8; ++mi)
    #pragma unroll
    for (int nj = 0; nj < 4; ++nj) acc[mi][nj] = (f32x4){0.f, 0.f, 0.f, 0.f};

  // staging registers for one half (2 p-groups)
  float4 s_p0[2], s_p1[2];
  uint4 s_q[2], s_r[2];

  auto genLoad = [&](int c, int ph) {
    const int col = c * 64 + ks_id * 32 + lq * 8;
    const int cb2 = col >> 1;
    #pragma unroll
    for (int i = 0; i < 2; ++i) {
      const int p = ph * 2 + i;
      const int r = (p * 2 + hi_id) * 16 + ln;
      const int bb = r & 63;
      const int kg = k0 + (r >> 6);
      s_p0[i] = *(const float4*)(Pf + bb * 512 + col);
      s_p1[i] = *(const float4*)(Pf + bb * 512 + col + 4);
      s_q[i]  = *(const uint4*)(Q + (kg << 8) + cb2);
      s_r[i]  = *(const uint4*)(Rm + (kg << 8) + cb2);
    }
  };
  auto genStore = [&](int ph, unsigned short* buf) {
    #pragma unroll
    for (int i = 0; i < 2; ++i) {
      const int p = ph * 2 + i;
      const float rp_ = rb[p];
      unsigned d[4];
      float z0, z1;
      z0 = fmaf(-rp_, bflo(s_r[i].x), s_p0[i].x + bflo(s_q[i].x));
      z1 = fmaf(-rp_, bfhi(s_r[i].x), s_p0[i].y + bfhi(s_q[i].x));
      d[0] = pack2(fmaxf(z0, 0.f), fmaxf(z1, 0.f));
      z0 = fmaf(-rp_, bflo(s_r[i].y), s_p0[i].z + bflo(s_q[i].y));
      z1 = fmaf(-rp_, bfhi(s_r[i].y), s_p0[i].w + bfhi(s_q[i].y));
      d[1] = pack2(fmaxf(z0, 0.f), fmaxf(z1, 0.f));
      z0 = fmaf(-rp_, bflo(s_r[i].z), s_p1[i].x + bflo(s_q[i].z));
      z1 = fmaf(-rp_, bfhi(s_r[i].z), s_p1[i].y + bfhi(s_q[i].z));
      d[2] = pack2(fmaxf(z0, 0.f), fmaxf(z1, 0.f));
      z0 = fmaf(-rp_, bflo(s_r[i].w), s_p1[i].z + bflo(s_q[i].w));
      z1 = fmaf(-rp_, bfhi(s_r[i].w), s_p1[i].w + bfhi(s_q[i].w));
      d[3] = pack2(fmaxf(z0, 0.f), fmaxf(z1, 0.f));
      // fragment group id = p*256 + t (== ((mi*2+ks_id)*4+lq)*16+ln, mi=p*2+hi_id)
      *(uint4*)(&buf[(size_t)(p * 256 + t) * 8]) = make_uint4(d[0], d[1], d[2], d[3]);
    }
  };
  auto mfma_half = [&](const unsigned short* buf, int c, int ks) {
    short8 afr[8];
    #pragma unroll
    for (int mi = 0; mi < 8; ++mi)
      afr[mi] = *(const short8*)(buf + (size_t)((((mi * 2 + ks) * 4 + lq) * 16 + ln) * 8));
    short8 bfr[4];
    #pragma unroll
    for (int nj = 0; nj < 4; ++nj)
      bfr[nj] = *(const short8*)(W2t + (size_t)(w * 64 + nj * 16 + ln) * 512 + c * 64 + ks * 32 + lq * 8);
    #pragma unroll
    for (int mi = 0; mi < 8; ++mi)
      #pragma unroll
      for (int nj = 0; nj < 4; ++nj)
        acc[mi][nj] = __builtin_amdgcn_mfma_f32_16x16x32_bf16(afr[mi], bfr[nj], acc[mi][nj], 0, 0, 0);
  };

  // stage chunk 0 directly
  genLoad(0, 0); genStore(0, A_lds[0]);
  genLoad(0, 1); genStore(1, A_lds[0]);

  for (int c = 0; c < 8; ++c) {
    __syncthreads();  // writes of buf[c&1] visible; prior reads of buf[(c+1)&1] done
    unsigned short* nbuf = A_lds[(c + 1) & 1];
    const unsigned short* buf = A_lds[c & 1];
    if (c < 7) genLoad(c + 1, 0);   // loads in flight under MFMA ks=0
    mfma_half(buf, c, 0);
    if (c < 7) { genStore(0, nbuf); genLoad(c + 1, 1); }  // write half0; issue half1
    mfma_half(buf, c, 1);
    if (c < 7) genStore(1, nbuf);
  }

  // epilogue: u = relu(t2[o]*acc + c2[o]) * W3[o]; reduce over o
  float t2v[4], c2v[4], w3v[4];
  #pragma unroll
  for (int nj = 0; nj < 4; ++nj) {
    int o = w * 64 + nj * 16 + ln;
    t2v[nj] = t2[o];
    c2v[nj] = c2[o];
    w3v[nj] = W3[o];
  }
  #pragma unroll
  for (int mi = 0; mi < 8; ++mi) {
    float s[4] = {0.f, 0.f, 0.f, 0.f};
    #pragma unroll
    for (int nj = 0; nj < 4; ++nj)
      #pragma unroll
      for (int r = 0; r < 4; ++r) {
        float u = fmaf(t2v[nj], acc[mi][nj][r], c2v[nj]);
        u = fmaxf(u, 0.f);
        s[r] = fmaf(u, w3v[nj], s[r]);
      }
    #pragma unroll
    for (int r = 0; r < 4; ++r) {
      #pragma unroll
      for (int m = 1; m < 16; m <<= 1) s[r] += __shfl_xor(s[r], m, 64);
    }
    if (ln == 0) {
      #pragma unroll
      for (int r = 0; r < 4; ++r) partial[w][mi * 16 + lq * 4 + r] = s[r];
    }
  }
  __syncthreads();
  if (t < 128) {
    out[(t & 63) * 2048 + k0 + (t >> 6)] =
        partial[0][t] + partial[1][t] + partial[2][t] + partial[3][t] + b3[0];
  }
}

extern "C" void kernel_launch(void* const* d_in, const int* in_sizes, int n_in,
                              void* d_out, int out_size, void* d_ws, size_t ws_size,
                              hipStream_t stream) {
  const float* rep   = (const float*)d_in[0];
  const float* emb   = (const float*)d_in[1];
  const float* W1    = (const float*)d_in[2];
  const float* b1    = (const float*)d_in[3];
  const float* g1    = (const float*)d_in[4];
  const float* beta1 = (const float*)d_in[5];
  const float* m1    = (const float*)d_in[6];
  const float* v1    = (const float*)d_in[7];
  const float* W2    = (const float*)d_in[8];
  const float* b2    = (const float*)d_in[9];
  const float* g2    = (const float*)d_in[10];
  const float* beta2 = (const float*)d_in[11];
  const float* m2    = (const float*)d_in[12];
  const float* v2    = (const float*)d_in[13];
  const float* W3    = (const float*)d_in[14];
  const float* b3    = (const float*)d_in[15];
  float* out = (float*)d_out;
  char* ws = (char*)d_ws;

  float* Pf            = (float*)(ws + 0);           // 64x512 f32 (128 KB)
  unsigned* Q          = (unsigned*)(ws + 131072);   // 2048x256 pairs (2 MB)
  unsigned* R          = (unsigned*)(ws + 2228224);  // 2048x256 pairs (2 MB)
  unsigned short* W2t  = (unsigned short*)(ws + 4325376);  // 256x512 bf16 (256 KB)
  float* t2            = (float*)(ws + 4587520);     // 256 f32
  float* c2            = (float*)(ws + 4588544);     // 256 f32

  prep2<<<577, 256, 0, stream>>>(emb, W1, g1, v1, b1, m1, beta1, W2, g2, v2,
                                 b2, m2, beta2, Q, R, W2t, t2, c2, Pf);
  p_gemm<<<512, 256, 0, stream>>>(rep, R, Pf);
  fused_main<<<1024, 256, 0, stream>>>(rep, Pf, Q, R, W2t, t2, c2, W3, b3, out);
}

// Round 8
// 171.384 us; speedup vs baseline: 1.6747x; 1.0653x over previous
//
#include <hip/hip_runtime.h>

#define EPS 1e-5f
// B=64, D=2048, E=64, H1=512, H2=256

typedef __attribute__((ext_vector_type(8))) short short8;
typedef __attribute__((ext_vector_type(4))) float f32x4;

__device__ __forceinline__ float bflo(unsigned u) { return __uint_as_float(u << 16); }
__device__ __forceinline__ float bfhi(unsigned u) { return __uint_as_float(u & 0xffff0000u); }
__device__ __forceinline__ unsigned short f2bf(float f) {
  unsigned u = __float_as_uint(f);
  u = u + 0x7FFFu + ((u >> 16) & 1u);  // RNE
  return (unsigned short)(u >> 16);
}
__device__ __forceinline__ unsigned pack2(float a, float b) {
  return (unsigned)f2bf(a) | ((unsigned)f2bf(b) << 16);
}

// ---------------- prep2: Q(+pbias), R, W2t, t2/c2, Pf-zero (R6/R7-proven) ----------------
__global__ __launch_bounds__(256) void prep2(
    const float* __restrict__ emb, const float* __restrict__ W1,
    const float* __restrict__ g1, const float* __restrict__ v1,
    const float* __restrict__ b1, const float* __restrict__ m1,
    const float* __restrict__ beta1,
    const float* __restrict__ W2,
    const float* __restrict__ g2, const float* __restrict__ v2,
    const float* __restrict__ b2, const float* __restrict__ m2,
    const float* __restrict__ beta2,
    unsigned* __restrict__ Q, unsigned* __restrict__ R,
    unsigned short* __restrict__ W2t,
    float* __restrict__ t2, float* __restrict__ c2, float* __restrict__ Pf) {
  __shared__ float smem[256];
  const int x = blockIdx.x, t = threadIdx.x;
  if (x < 512) {
    const int k0 = x * 4;
    smem[t] = emb[x * 256 + t];  // 4 emb rows, coalesced
    __syncthreads();
    const int h = t * 2;
    const float a0 = g1[h] * rsqrtf(v1[h] + EPS);
    const float a1 = g1[h + 1] * rsqrtf(v1[h + 1] + EPS);
    const float pb0 = a0 * (b1[h] - m1[h]) + beta1[h];
    const float pb1 = a1 * (b1[h + 1] - m1[h + 1]) + beta1[h + 1];
    const float* We = W1 + 2048 * 512;
    float acc0[4], acc1[4];
    #pragma unroll
    for (int k = 0; k < 4; ++k) { acc0[k] = 0.f; acc1[k] = 0.f; }
    #pragma unroll 4
    for (int e = 0; e < 64; ++e) {
      float2 wv = *(const float2*)(We + e * 512 + h);
      #pragma unroll
      for (int k = 0; k < 4; ++k) {
        float ev = smem[k * 64 + e];  // LDS broadcast
        acc0[k] = fmaf(ev, wv.x, acc0[k]);
        acc1[k] = fmaf(ev, wv.y, acc1[k]);
      }
    }
    #pragma unroll
    for (int k = 0; k < 4; ++k) {
      // pbias folded into Q: h1bn = Pf + (Q+pbias) - rep*R
      Q[(k0 + k) * 256 + t] = pack2(a0 * acc0[k] + pb0, a1 * acc1[k] + pb1);
      float2 wv = *(const float2*)(W1 + (size_t)(k0 + k) * 512 + h);
      R[(k0 + k) * 256 + t] = pack2(a0 * wv.x, a1 * wv.y);
    }
  } else if (x < 576) {
    const int h0 = (x - 512) * 8;
    const int o = t;
    unsigned d[4];
    #pragma unroll
    for (int i = 0; i < 4; ++i) {
      float v0 = W2[(h0 + 2 * i) * 256 + o];      // coalesced across o
      float v1_ = W2[(h0 + 2 * i + 1) * 256 + o];
      d[i] = pack2(v0, v1_);
    }
    *(uint4*)(W2t + o * 512 + h0) = make_uint4(d[0], d[1], d[2], d[3]);  // 16B/thread
  } else {
    float tv = g2[t] * rsqrtf(v2[t] + EPS);
    t2[t] = tv;
    c2[t] = tv * (b2[t] - m2[t]) + beta2[t];
    f32x4 z = (f32x4){0.f, 0.f, 0.f, 0.f};
    #pragma unroll 8
    for (int j = 0; j < 32; ++j)
      *(f32x4*)(Pf + ((size_t)(j * 256 + t)) * 4) = z;  // zero 64x512 f32
  }
}

// ---------------- p_gemm: Pf += rep @ R (split-K, atomic f32) — R3/R6/R7-proven ----------------
__global__ __launch_bounds__(256) void p_gemm(
    const float* __restrict__ rep, const unsigned* __restrict__ R,
    float* __restrict__ Pf) {
  __shared__ float red[4][512];
  const int b = blockIdx.x >> 3, ksl = blockIdx.x & 7;
  const int t = threadIdx.x, lane = t & 63, kq = t >> 6;
  const int kbase = ksl * 256 + kq * 64;
  const unsigned* Rp = R + (size_t)kbase * 256 + lane * 4;
  const float* rp = rep + b * 2048 + kbase;
  float acc[8];
  #pragma unroll
  for (int i = 0; i < 8; ++i) acc[i] = 0.f;
  #pragma unroll 8
  for (int k = 0; k < 64; ++k) {
    uint4 rv = *(const uint4*)(Rp + (size_t)k * 256);
    float rk = rp[k];  // wave-uniform scalar
    acc[0] = fmaf(rk, bflo(rv.x), acc[0]); acc[1] = fmaf(rk, bfhi(rv.x), acc[1]);
    acc[2] = fmaf(rk, bflo(rv.y), acc[2]); acc[3] = fmaf(rk, bfhi(rv.y), acc[3]);
    acc[4] = fmaf(rk, bflo(rv.z), acc[4]); acc[5] = fmaf(rk, bfhi(rv.z), acc[5]);
    acc[6] = fmaf(rk, bflo(rv.w), acc[6]); acc[7] = fmaf(rk, bfhi(rv.w), acc[7]);
  }
  *(f32x4*)(&red[kq][lane * 8])     = (f32x4){acc[0], acc[1], acc[2], acc[3]};
  *(f32x4*)(&red[kq][lane * 8 + 4]) = (f32x4){acc[4], acc[5], acc[6], acc[7]};
  __syncthreads();
  {
    const int h = t * 2;
    float s0 = red[0][h] + red[1][h] + red[2][h] + red[3][h];
    float s1 = red[0][h + 1] + red[1][h + 1] + red[2][h + 1] + red[3][h + 1];
    atomicAdd(&Pf[b * 512 + h], s0);
    atomicAdd(&Pf[b * 512 + h + 1], s1);
  }
}

// ---------------- pf2p: pack Pf (f32) -> P (bf16 pairs) ----------------
__global__ __launch_bounds__(256) void pf2p(const float* __restrict__ Pf,
                                            unsigned* __restrict__ P) {
  const int i = blockIdx.x * 256 + threadIdx.x;  // 16384 pairs
  float2 v = *(const float2*)(Pf + 2 * i);
  P[i] = pack2(v.x, v.y);
}

// ---------------- fused main (v6: chunk-ahead register prefetch) ----------------
// Block: 2 k x 64 b = 128 rows, N=256, K=512 in 8 chunks of 64. 4 waves, o-tile 64/wave.
// Steady state per chunk c: s_* already holds chunk c+1 data (issued during chunk c-1's
// MFMA) -> barrier -> pack+ds_write c+1 (no vmcnt stall) -> issue loads c+2 -> MFMA(c).
// The ~300cy load latency is covered by a full chunk of MFMA (~640cy across 2 waves).
__global__ __launch_bounds__(256, 2) void fused_main(
    const float* __restrict__ rep,
    const unsigned* __restrict__ P,
    const unsigned* __restrict__ Q,
    const unsigned* __restrict__ Rm,
    const unsigned short* __restrict__ W2t,
    const float* __restrict__ t2, const float* __restrict__ c2,
    const float* __restrict__ W3, const float* __restrict__ b3,
    float* __restrict__ out) {
  __shared__ unsigned short A_lds[2][8192];  // 2 x 16KB, fragment-ordered
  __shared__ float partial[4][128];

  const int t = threadIdx.x;
  const int w = t >> 6;
  const int ln = t & 15;
  const int lq = (t >> 4) & 3;
  const int ks_id = w & 1;   // gen role: 32-col half of 64-chunk
  const int hi_id = w >> 1;  // gen role: mi parity
  const int k0 = blockIdx.x * 2;

  // rep scalars for this thread's 4 generated rows (regs, no LDS)
  float rb[4];
  #pragma unroll
  for (int p = 0; p < 4; ++p) {
    int r = (p * 2 + hi_id) * 16 + ln;
    rb[p] = rep[(r & 63) * 2048 + k0 + (r >> 6)];
  }

  f32x4 acc[8][4];
  #pragma unroll
  for (int mi = 0; mi < 8; ++mi)
    #pragma unroll
    for (int nj = 0; nj < 4; ++nj) acc[mi][nj] = (f32x4){0.f, 0.f, 0.f, 0.f};

  // one full chunk of staging: 12 uint4 = 48 VGPR
  uint4 s_p[4], s_q[4], s_r[4];

  auto genLoad = [&](int c) {
    const int cb2 = (c * 64 + ks_id * 32 + lq * 8) >> 1;
    #pragma unroll
    for (int p = 0; p < 4; ++p) {
      const int r = (p * 2 + hi_id) * 16 + ln;
      const int bb = r & 63;
      const int kg = k0 + (r >> 6);
      s_p[p] = *(const uint4*)(P + (bb << 8) + cb2);
      s_q[p] = *(const uint4*)(Q + (kg << 8) + cb2);
      s_r[p] = *(const uint4*)(Rm + (kg << 8) + cb2);
    }
  };
  auto genStore = [&](unsigned short* buf) {
    #pragma unroll
    for (int p = 0; p < 4; ++p) {
      const float rp_ = rb[p];
      unsigned d[4];
      float z0, z1;
      z0 = fmaf(-rp_, bflo(s_r[p].x), bflo(s_p[p].x) + bflo(s_q[p].x));
      z1 = fmaf(-rp_, bfhi(s_r[p].x), bfhi(s_p[p].x) + bfhi(s_q[p].x));
      d[0] = pack2(fmaxf(z0, 0.f), fmaxf(z1, 0.f));
      z0 = fmaf(-rp_, bflo(s_r[p].y), bflo(s_p[p].y) + bflo(s_q[p].y));
      z1 = fmaf(-rp_, bfhi(s_r[p].y), bfhi(s_p[p].y) + bfhi(s_q[p].y));
      d[1] = pack2(fmaxf(z0, 0.f), fmaxf(z1, 0.f));
      z0 = fmaf(-rp_, bflo(s_r[p].z), bflo(s_p[p].z) + bflo(s_q[p].z));
      z1 = fmaf(-rp_, bfhi(s_r[p].z), bfhi(s_p[p].z) + bfhi(s_q[p].z));
      d[2] = pack2(fmaxf(z0, 0.f), fmaxf(z1, 0.f));
      z0 = fmaf(-rp_, bflo(s_r[p].w), bflo(s_p[p].w) + bflo(s_q[p].w));
      z1 = fmaf(-rp_, bfhi(s_r[p].w), bfhi(s_p[p].w) + bfhi(s_q[p].w));
      d[3] = pack2(fmaxf(z0, 0.f), fmaxf(z1, 0.f));
      // fragment group id = p*256 + t (== ((mi*2+ks_id)*4+lq)*16+ln, mi=p*2+hi_id)
      *(uint4*)(&buf[(size_t)(p * 256 + t) * 8]) = make_uint4(d[0], d[1], d[2], d[3]);
    }
  };
  auto mfma_chunk = [&](const unsigned short* buf, int c) {
    #pragma unroll
    for (int ks = 0; ks < 2; ++ks) {
      short8 afr[8];
      #pragma unroll
      for (int mi = 0; mi < 8; ++mi)
        afr[mi] = *(const short8*)(buf + (size_t)((((mi * 2 + ks) * 4 + lq) * 16 + ln) * 8));
      short8 bfr[4];
      #pragma unroll
      for (int nj = 0; nj < 4; ++nj)
        bfr[nj] = *(const short8*)(W2t + (size_t)(w * 64 + nj * 16 + ln) * 512 + c * 64 + ks * 32 + lq * 8);
      #pragma unroll
      for (int mi = 0; mi < 8; ++mi)
        #pragma unroll
        for (int nj = 0; nj < 4; ++nj)
          acc[mi][nj] = __builtin_amdgcn_mfma_f32_16x16x32_bf16(afr[mi], bfr[nj], acc[mi][nj], 0, 0, 0);
    }
  };

  // prologue: chunk0 staged (one-time vmcnt stall), chunk1 loads in flight
  genLoad(0);
  genStore(A_lds[0]);
  genLoad(1);

  for (int c = 0; c < 8; ++c) {
    __syncthreads();  // writes of buf[c&1] visible; prior reads of buf[(c+1)&1] done
    if (c < 7) genStore(A_lds[(c + 1) & 1]);  // data loaded a full chunk ago
    if (c < 6) genLoad(c + 2);                // issue early; MFMA below covers latency
    mfma_chunk(A_lds[c & 1], c);
  }

  // epilogue: u = relu(t2[o]*acc + c2[o]) * W3[o]; reduce over o
  float t2v[4], c2v[4], w3v[4];
  #pragma unroll
  for (int nj = 0; nj < 4; ++nj) {
    int o = w * 64 + nj * 16 + ln;
    t2v[nj] = t2[o];
    c2v[nj] = c2[o];
    w3v[nj] = W3[o];
  }
  #pragma unroll
  for (int mi = 0; mi < 8; ++mi) {
    float s[4] = {0.f, 0.f, 0.f, 0.f};
    #pragma unroll
    for (int nj = 0; nj < 4; ++nj)
      #pragma unroll
      for (int r = 0; r < 4; ++r) {
        float u = fmaf(t2v[nj], acc[mi][nj][r], c2v[nj]);
        u = fmaxf(u, 0.f);
        s[r] = fmaf(u, w3v[nj], s[r]);
      }
    #pragma unroll
    for (int r = 0; r < 4; ++r) {
      #pragma unroll
      for (int m = 1; m < 16; m <<= 1) s[r] += __shfl_xor(s[r], m, 64);
    }
    if (ln == 0) {
      #pragma unroll
      for (int r = 0; r < 4; ++r) partial[w][mi * 16 + lq * 4 + r] = s[r];
    }
  }
  __syncthreads();
  if (t < 128) {
    out[(t & 63) * 2048 + k0 + (t >> 6)] =
        partial[0][t] + partial[1][t] + partial[2][t] + partial[3][t] + b3[0];
  }
}

extern "C" void kernel_launch(void* const* d_in, const int* in_sizes, int n_in,
                              void* d_out, int out_size, void* d_ws, size_t ws_size,
                              hipStream_t stream) {
  const float* rep   = (const float*)d_in[0];
  const float* emb   = (const float*)d_in[1];
  const float* W1    = (const float*)d_in[2];
  const float* b1    = (const float*)d_in[3];
  const float* g1    = (const float*)d_in[4];
  const float* beta1 = (const float*)d_in[5];
  const float* m1    = (const float*)d_in[6];
  const float* v1    = (const float*)d_in[7];
  const float* W2    = (const float*)d_in[8];
  const float* b2    = (const float*)d_in[9];
  const float* g2    = (const float*)d_in[10];
  const float* beta2 = (const float*)d_in[11];
  const float* m2    = (const float*)d_in[12];
  const float* v2    = (const float*)d_in[13];
  const float* W3    = (const float*)d_in[14];
  const float* b3    = (const float*)d_in[15];
  float* out = (float*)d_out;
  char* ws = (char*)d_ws;

  float* Pf            = (float*)(ws + 0);           // 64x512 f32 (128 KB)
  unsigned* P          = (unsigned*)(ws + 131072);   // 64x256 bf16 pairs (64 KB)
  unsigned* Q          = (unsigned*)(ws + 196608);   // 2048x256 pairs (2 MB)
  unsigned* R          = (unsigned*)(ws + 2293760);  // 2048x256 pairs (2 MB)
  unsigned short* W2t  = (unsigned short*)(ws + 4390912);  // 256x512 bf16 (256 KB)
  float* t2            = (float*)(ws + 4653056);     // 256 f32
  float* c2            = (float*)(ws + 4654080);     // 256 f32

  prep2<<<577, 256, 0, stream>>>(emb, W1, g1, v1, b1, m1, beta1, W2, g2, v2,
                                 b2, m2, beta2, Q, R, W2t, t2, c2, Pf);
  p_gemm<<<512, 256, 0, stream>>>(rep, R, Pf);
  pf2p<<<64, 256, 0, stream>>>(Pf, P);
  fused_main<<<1024, 256, 0, stream>>>(rep, P, Q, R, W2t, t2, c2, W3, b3, out);
}